// Round 1
// baseline (3762.690 us; speedup 1.0000x reference)
//
#include <hip/hip_runtime.h>
#include <stdint.h>

typedef float f32x4 __attribute__((ext_vector_type(4)));

#define FP8MAX 448.0f

__device__ __forceinline__ float amax_scale(float amax) {
    return FP8MAX / fmaxf(amax, 1e-12f);
}

// ---------------- amax (|x| max over tensor) ----------------
__global__ void amax_kernel(const float* __restrict__ x, long n, float* __restrict__ out) {
    long idx = (long)blockIdx.x * blockDim.x + threadIdx.x;
    long stride = (long)gridDim.x * blockDim.x;
    float m = 0.0f;
    for (long j = idx * 4; j < n; j += stride * 4) {
        f32x4 v = *(const f32x4*)(x + j);
        m = fmaxf(m, fmaxf(fmaxf(__builtin_fabsf(v.x), __builtin_fabsf(v.y)),
                           fmaxf(__builtin_fabsf(v.z), __builtin_fabsf(v.w))));
    }
#pragma unroll
    for (int o = 32; o > 0; o >>= 1) m = fmaxf(m, __shfl_xor(m, o, 64));
    if ((threadIdx.x & 63) == 0) atomicMax((int*)out, __float_as_int(m));
}

// ---------------- quantize fp32 -> fp8 e4m3 (row-major, same layout) ----------------
__global__ void quant_kernel(const float* __restrict__ x, uint8_t* __restrict__ q,
                             const float* __restrict__ amaxp, long n) {
    const float s = amax_scale(*amaxp);
    long idx = (long)blockIdx.x * blockDim.x + threadIdx.x;
    long stride = (long)gridDim.x * blockDim.x;
    for (long j = idx * 4; j < n; j += stride * 4) {
        f32x4 v = *(const f32x4*)(x + j);
        int p0 = __builtin_amdgcn_cvt_pk_fp8_f32(v.x * s, v.y * s, 0, false);
        int p1 = __builtin_amdgcn_cvt_pk_fp8_f32(v.z * s, v.w * s, 0, false);
        *(uint32_t*)(q + j) = (uint32_t)(p0 & 0xffff) | ((uint32_t)p1 << 16);
    }
}

// ---------------- quantize + transpose: w[R][C] fp32 -> wqT[C][R] fp8 ----------------
__global__ void quant_transpose_kernel(const float* __restrict__ w, uint8_t* __restrict__ wqT,
                                       const float* __restrict__ amaxp, int R, int C) {
    __shared__ float tile[32][33];
    const float sc = amax_scale(*amaxp);
    const int col0 = blockIdx.x * 32;
    const int row0 = blockIdx.y * 32;
    const int tx = threadIdx.x & 31;
    const int ty = threadIdx.x >> 5;  // 0..7
#pragma unroll
    for (int i = 0; i < 4; i++)
        tile[ty + i * 8][tx] = w[(long)(row0 + ty + i * 8) * C + col0 + tx];
    __syncthreads();
    const int c  = threadIdx.x >> 3;        // 0..31 (output row = col0+c)
    const int kk = (threadIdx.x & 7) * 4;   // 0..28 (output col group)
    float v0 = tile[kk + 0][c] * sc, v1 = tile[kk + 1][c] * sc;
    float v2 = tile[kk + 2][c] * sc, v3 = tile[kk + 3][c] * sc;
    int p0 = __builtin_amdgcn_cvt_pk_fp8_f32(v0, v1, 0, false);
    int p1 = __builtin_amdgcn_cvt_pk_fp8_f32(v2, v3, 0, false);
    *(uint32_t*)(wqT + (long)(col0 + c) * R + row0 + kk) =
        (uint32_t)(p0 & 0xffff) | ((uint32_t)p1 << 16);
}

// ---------------- fp8 GEMM: C[M][N] = dequant(A[M][K] @ Bt[N][K]^T) + bias ----------------
__device__ __forceinline__ void lds_dma16(const void* g, void* l) {
    __builtin_amdgcn_global_load_lds((__attribute__((address_space(1))) void*)(void*)g,
                                     (__attribute__((address_space(3))) void*)l, 16, 0, 0);
}

template <bool RELU, bool AMAX>
__global__ __launch_bounds__(256) void gemm_fp8_kernel(
    const uint8_t* __restrict__ A, const uint8_t* __restrict__ Bt,
    float* __restrict__ C, const float* __restrict__ bias,
    const float* __restrict__ amaxA, const float* __restrict__ amaxB,
    float* __restrict__ amaxOut, int M, int N, int K) {
    // 128x128 block tile, BK=64 fp8 bytes. 4 waves in 2x2, each wave 64x64 via 4x4
    // mfma_f32_16x16x32_fp8_fp8. LDS columns xor-swizzled in 16B units so the
    // ds_read_b64 fragment reads are bank-uniform while global_load_lds stays a
    // contiguous lane*16B DMA (wave-uniform-base constraint, m104).
    __shared__ uint8_t As[128 * 64];
    __shared__ uint8_t Bs[128 * 64];
    const int t = threadIdx.x;
    const int lane = t & 63;
    const int wave = t >> 6;
    const int bm = blockIdx.x, bn = blockIdx.y;

    const int srow = t >> 2;                     // 0..63 (tile row this thread stages)
    const int sunit = (t & 3) ^ (srow & 3);      // xor-swizzled 16B k-unit to fetch
    const uint8_t* ag = A + (long)(bm * 128 + srow) * K + sunit * 16;
    const uint8_t* bg = Bt + (long)(bn * 128 + srow) * K + sunit * 16;
    uint8_t* asd = As + t * 16;
    uint8_t* bsd = Bs + t * 16;
    const long half_off = (long)64 * K;          // rows 64..127 staged by second DMA

    f32x4 acc[4][4] = {};

    const int wm = wave & 1, wn = wave >> 1;
    const int lrow = lane & 15;
    const int xr = lrow & 3;
    int co[2];
#pragma unroll
    for (int ks = 0; ks < 2; ks++)
        co[ks] = (((ks * 2 + (lane >> 5)) ^ xr) << 4) | (((lane >> 4) & 1) << 3);
    const int arow0 = (wm * 64 + lrow) * 64;
    const int brow0 = (wn * 64 + lrow) * 64;

    for (int k0 = 0; k0 < K; k0 += 64) {
        __syncthreads();
        lds_dma16(ag, asd);
        lds_dma16(ag + half_off, asd + 64 * 64);
        lds_dma16(bg, bsd);
        lds_dma16(bg + half_off, bsd + 64 * 64);
        ag += 64; bg += 64;
        __syncthreads();
#pragma unroll
        for (int ks = 0; ks < 2; ks++) {
            long av[4], bv[4];
#pragma unroll
            for (int i = 0; i < 4; i++)
                av[i] = *(const long*)(As + arow0 + i * 16 * 64 + co[ks]);
#pragma unroll
            for (int j = 0; j < 4; j++)
                bv[j] = *(const long*)(Bs + brow0 + j * 16 * 64 + co[ks]);
#pragma unroll
            for (int i = 0; i < 4; i++)
#pragma unroll
                for (int j = 0; j < 4; j++)
                    acc[i][j] = __builtin_amdgcn_mfma_f32_16x16x32_fp8_fp8(
                        av[i], bv[j], acc[i][j], 0, 0, 0);
        }
    }

    // epilogue: dequant scale + bias (+relu) (+fused amax), C/D layout:
    // col = lane&15, row = (lane>>4)*4 + reg  (16x16 shape, dtype-independent)
    const float inv = 1.0f / (amax_scale(*amaxA) * amax_scale(*amaxB));
    const int rg = (lane >> 4) * 4;
    const int cl = lane & 15;
    const int orow = bm * 128 + wm * 64 + rg;
    const int ocol = bn * 128 + wn * 64 + cl;
    float lmax = 0.0f;
#pragma unroll
    for (int j = 0; j < 4; j++) {
        const float bv = bias[ocol + j * 16];
#pragma unroll
        for (int i = 0; i < 4; i++) {
#pragma unroll
            for (int r = 0; r < 4; r++) {
                float v = acc[i][j][r] * inv + bv;
                if (RELU) v = fmaxf(v, 0.0f);
                C[(long)(orow + i * 16 + r) * N + ocol + j * 16] = v;
                if (AMAX) lmax = fmaxf(lmax, __builtin_fabsf(v));
            }
        }
    }
    if (AMAX) {
#pragma unroll
        for (int o = 32; o > 0; o >>= 1) lmax = fmaxf(lmax, __shfl_xor(lmax, o, 64));
        if (lane == 0) atomicMax((int*)amaxOut, __float_as_int(lmax));
    }
}

extern "C" void kernel_launch(void* const* d_in, const int* in_sizes, int n_in,
                              void* d_out, int out_size, void* d_ws, size_t ws_size,
                              hipStream_t stream) {
    const float* x  = (const float*)d_in[0];
    const float* w1 = (const float*)d_in[1];
    const float* b1 = (const float*)d_in[2];
    const float* w2 = (const float*)d_in[3];
    const float* b2 = (const float*)d_in[4];
    float* out = (float*)d_out;

    const int N1 = in_sizes[2];       // 16384
    const int N2 = in_sizes[4];       // 4096
    const int K1 = in_sizes[1] / N1;  // 4096
    const int M  = in_sizes[0] / K1;  // 8192

    uint8_t* ws = (uint8_t*)d_ws;
    float* amax_x  = (float*)(ws + 0);
    float* amax_w1 = (float*)(ws + 4);
    float* amax_w2 = (float*)(ws + 8);
    float* amax_h  = (float*)(ws + 12);
    size_t off = 256;
    uint8_t* xq   = ws + off; off += (size_t)M * K1;        // 33.5 MB
    uint8_t* w1qT = ws + off; off += (size_t)K1 * N1;       // 67 MB
    uint8_t* w2qT = ws + off; off += (size_t)N1 * N2;       // 67 MB
    uint8_t* hq   = ws + off; off += (size_t)M * N1;        // 134 MB
    float*   h    = (float*)(ws + off); off += (size_t)M * N1 * 4;  // 537 MB

    hipMemsetAsync(d_ws, 0, 256, stream);  // zero amax slots (ws is poisoned 0xAA)

    amax_kernel<<<1024, 256, 0, stream>>>(x,  (long)M * K1,  amax_x);
    amax_kernel<<<1024, 256, 0, stream>>>(w1, (long)K1 * N1, amax_w1);
    amax_kernel<<<1024, 256, 0, stream>>>(w2, (long)N1 * N2, amax_w2);

    quant_kernel<<<2048, 256, 0, stream>>>(x, xq, amax_x, (long)M * K1);
    quant_transpose_kernel<<<dim3(N1 / 32, K1 / 32), 256, 0, stream>>>(w1, w1qT, amax_w1, K1, N1);
    quant_transpose_kernel<<<dim3(N2 / 32, N1 / 32), 256, 0, stream>>>(w2, w2qT, amax_w2, N1, N2);

    gemm_fp8_kernel<true, true><<<dim3(M / 128, N1 / 128), 256, 0, stream>>>(
        xq, w1qT, h, b1, amax_x, amax_w1, amax_h, M, N1, K1);

    quant_kernel<<<4096, 256, 0, stream>>>(h, hq, amax_h, (long)M * N1);

    gemm_fp8_kernel<false, false><<<dim3(M / 128, N2 / 128), 256, 0, stream>>>(
        hq, w2qT, out, b2, amax_h, amax_w2, nullptr, M, N2, N1);
}

// Round 2
// 2196.121 us; speedup vs baseline: 1.7133x; 1.7133x over previous
//
#include <hip/hip_runtime.h>
#include <stdint.h>

typedef float f32x4 __attribute__((ext_vector_type(4)));
typedef int v4i __attribute__((ext_vector_type(4)));
typedef int v8i __attribute__((ext_vector_type(8)));

#define FP8MAX 448.0f

__device__ __forceinline__ float amax_scale(float amax) {
    return FP8MAX / fmaxf(amax, 1e-12f);
}

// ---------------- amax (|x| max over tensor) ----------------
__global__ void amax_kernel(const float* __restrict__ x, long n, float* __restrict__ out) {
    long idx = (long)blockIdx.x * blockDim.x + threadIdx.x;
    long stride = (long)gridDim.x * blockDim.x;
    float m = 0.0f;
    for (long j = idx * 4; j < n; j += stride * 4) {
        f32x4 v = *(const f32x4*)(x + j);
        m = fmaxf(m, fmaxf(fmaxf(__builtin_fabsf(v.x), __builtin_fabsf(v.y)),
                           fmaxf(__builtin_fabsf(v.z), __builtin_fabsf(v.w))));
    }
#pragma unroll
    for (int o = 32; o > 0; o >>= 1) m = fmaxf(m, __shfl_xor(m, o, 64));
    if ((threadIdx.x & 63) == 0) atomicMax((int*)out, __float_as_int(m));
}

// ---------------- quantize fp32 -> fp8 e4m3 (row-major, same layout) ----------------
__global__ void quant_kernel(const float* __restrict__ x, uint8_t* __restrict__ q,
                             const float* __restrict__ amaxp, long n) {
    const float s = amax_scale(*amaxp);
    long idx = (long)blockIdx.x * blockDim.x + threadIdx.x;
    long stride = (long)gridDim.x * blockDim.x;
    for (long j = idx * 4; j < n; j += stride * 4) {
        f32x4 v = *(const f32x4*)(x + j);
        int p0 = __builtin_amdgcn_cvt_pk_fp8_f32(v.x * s, v.y * s, 0, false);
        int p1 = __builtin_amdgcn_cvt_pk_fp8_f32(v.z * s, v.w * s, 0, false);
        *(uint32_t*)(q + j) = (uint32_t)(p0 & 0xffff) | ((uint32_t)p1 << 16);
    }
}

// ---------------- quantize + transpose: w[R][C] fp32 -> wqT[C][R] fp8 ----------------
__global__ void quant_transpose_kernel(const float* __restrict__ w, uint8_t* __restrict__ wqT,
                                       const float* __restrict__ amaxp, int R, int C) {
    __shared__ float tile[32][33];
    const float sc = amax_scale(*amaxp);
    const int col0 = blockIdx.x * 32;
    const int row0 = blockIdx.y * 32;
    const int tx = threadIdx.x & 31;
    const int ty = threadIdx.x >> 5;  // 0..7
#pragma unroll
    for (int i = 0; i < 4; i++)
        tile[ty + i * 8][tx] = w[(long)(row0 + ty + i * 8) * C + col0 + tx];
    __syncthreads();
    const int c  = threadIdx.x >> 3;        // 0..31 (output row = col0+c)
    const int kk = (threadIdx.x & 7) * 4;   // 0..28 (output col group)
    float v0 = tile[kk + 0][c] * sc, v1 = tile[kk + 1][c] * sc;
    float v2 = tile[kk + 2][c] * sc, v3 = tile[kk + 3][c] * sc;
    int p0 = __builtin_amdgcn_cvt_pk_fp8_f32(v0, v1, 0, false);
    int p1 = __builtin_amdgcn_cvt_pk_fp8_f32(v2, v3, 0, false);
    *(uint32_t*)(wqT + (long)(col0 + c) * R + row0 + kk) =
        (uint32_t)(p0 & 0xffff) | ((uint32_t)p1 << 16);
}

// ---------------- MX-fp8 GEMM: C[M][N] = dequant(A[M][K] @ Bt[N][K]^T) + bias ----------------
__device__ __forceinline__ void lds_dma16(const void* g, void* l) {
    __builtin_amdgcn_global_load_lds((__attribute__((address_space(1))) void*)(void*)g,
                                     (__attribute__((address_space(3))) void*)l, 16, 0, 0);
}

template <bool RELU, bool AMAX>
__global__ __launch_bounds__(256) void gemm_mxfp8_kernel(
    const uint8_t* __restrict__ A, const uint8_t* __restrict__ Bt,
    float* __restrict__ C, const float* __restrict__ bias,
    const float* __restrict__ amaxA, const float* __restrict__ amaxB,
    float* __restrict__ amaxOut, int M, int N, int K) {
    // 128x128 block tile, BK=128 fp8 bytes. 4 waves in 2x2, each wave 64x64 via
    // 4x4 mfma_scale_f32_16x16x128_f8f6f4 (unit block scales => exact fp8 GEMM at
    // 2x the non-scaled fp8 rate). LDS rows are 128B = exactly 32 banks, so rows
    // alias; 16B-unit XOR swizzle (unit ^= row&7) makes every ds_read_b128 hit
    // each 4-bank group exactly 8x (the b128 phase floor). global_load_lds stays
    // a contiguous lane*16B DMA (wave-uniform-base constraint, m104).
    __shared__ __align__(16) uint8_t As[128 * 128];
    __shared__ __align__(16) uint8_t Bs[128 * 128];
    const int t = threadIdx.x;
    const int lane = t & 63;
    const int wave = t >> 6;
    const int bm = blockIdx.x, bn = blockIdx.y;

    // staging: DMA d (0..3) covers rows d*32 + (t>>3); storage unit = t&7 holds
    // global unit (t&7) ^ (row&7); row&7 == (t>>3)&7.
    const int rs = t >> 3;                       // 0..31
    const int us = (t & 7) ^ (rs & 7);
    const uint8_t* ag = A + (long)(bm * 128 + rs) * K + us * 16;
    const uint8_t* bg = Bt + (long)(bn * 128 + rs) * K + us * 16;
    uint8_t* asd = As + t * 16;
    uint8_t* bsd = Bs + t * 16;
    const long dstep = (long)32 * K;

    f32x4 acc[4][4] = {};

    const int wm = wave & 1, wn = wave >> 1;
    const int lrow = lane & 15;
    const int g = lane >> 4;                     // k-group: k bytes g*32..g*32+31
    const int x7 = lane & 7;                     // row&7 for this lane's frag rows
    const int roA = (wm * 64 + lrow) * 128;
    const int roB = (wn * 64 + lrow) * 128;
    const int u0 = ((2 * g + 0) ^ x7) * 16;      // swizzled offset of k-half 0
    const int u1 = ((2 * g + 1) ^ x7) * 16;      // swizzled offset of k-half 1

    for (int k0 = 0; k0 < K; k0 += 128) {
        __syncthreads();
#pragma unroll
        for (int d = 0; d < 4; d++) {
            lds_dma16(ag + d * dstep, asd + d * 4096);
            lds_dma16(bg + d * dstep, bsd + d * 4096);
        }
        ag += 128; bg += 128;
        __syncthreads();
        v8i af[4], bf[4];
#pragma unroll
        for (int i = 0; i < 4; i++) {
            const int ro = roA + i * 16 * 128;
            *(v4i*)&af[i] = *(const v4i*)(As + ro + u0);
            *((v4i*)&af[i] + 1) = *(const v4i*)(As + ro + u1);
        }
#pragma unroll
        for (int j = 0; j < 4; j++) {
            const int ro = roB + j * 16 * 128;
            *(v4i*)&bf[j] = *(const v4i*)(Bs + ro + u0);
            *((v4i*)&bf[j] + 1) = *(const v4i*)(Bs + ro + u1);
        }
#pragma unroll
        for (int i = 0; i < 4; i++)
#pragma unroll
            for (int j = 0; j < 4; j++)
                acc[i][j] = __builtin_amdgcn_mfma_scale_f32_16x16x128_f8f6f4(
                    af[i], bf[j], acc[i][j], 0, 0,      // cbsz=fp8, blgp=fp8
                    0, 0x7f7f7f7f, 0, 0x7f7f7f7f);      // unit E8M0 scales
    }

    // epilogue: dequant scale + bias (+relu) (+fused amax); 16x16 C/D layout:
    // col = lane&15, row = (lane>>4)*4 + reg (dtype-independent, m89)
    const float inv = 1.0f / (amax_scale(*amaxA) * amax_scale(*amaxB));
    const int rg = (lane >> 4) * 4;
    const int cl = lane & 15;
    const int orow = bm * 128 + wm * 64 + rg;
    const int ocol = bn * 128 + wn * 64 + cl;
    float lmax = 0.0f;
#pragma unroll
    for (int j = 0; j < 4; j++) {
        const float bv = bias[ocol + j * 16];
#pragma unroll
        for (int i = 0; i < 4; i++) {
#pragma unroll
            for (int r = 0; r < 4; r++) {
                float v = acc[i][j][r] * inv + bv;
                if (RELU) v = fmaxf(v, 0.0f);
                C[(long)(orow + i * 16 + r) * N + ocol + j * 16] = v;
                if (AMAX) lmax = fmaxf(lmax, __builtin_fabsf(v));
            }
        }
    }
    if (AMAX) {
#pragma unroll
        for (int o = 32; o > 0; o >>= 1) lmax = fmaxf(lmax, __shfl_xor(lmax, o, 64));
        if (lane == 0) atomicMax((int*)amaxOut, __float_as_int(lmax));
    }
}

extern "C" void kernel_launch(void* const* d_in, const int* in_sizes, int n_in,
                              void* d_out, int out_size, void* d_ws, size_t ws_size,
                              hipStream_t stream) {
    const float* x  = (const float*)d_in[0];
    const float* w1 = (const float*)d_in[1];
    const float* b1 = (const float*)d_in[2];
    const float* w2 = (const float*)d_in[3];
    const float* b2 = (const float*)d_in[4];
    float* out = (float*)d_out;

    const int N1 = in_sizes[2];       // 16384
    const int N2 = in_sizes[4];       // 4096
    const int K1 = in_sizes[1] / N1;  // 4096
    const int M  = in_sizes[0] / K1;  // 8192

    uint8_t* ws = (uint8_t*)d_ws;
    float* amax_x  = (float*)(ws + 0);
    float* amax_w1 = (float*)(ws + 4);
    float* amax_w2 = (float*)(ws + 8);
    float* amax_h  = (float*)(ws + 12);
    size_t off = 256;
    uint8_t* xq   = ws + off; off += (size_t)M * K1;        // 33.5 MB
    uint8_t* w1qT = ws + off; off += (size_t)K1 * N1;       // 67 MB
    uint8_t* w2qT = ws + off; off += (size_t)N1 * N2;       // 67 MB
    uint8_t* hq   = ws + off; off += (size_t)M * N1;        // 134 MB
    float*   h    = (float*)(ws + off); off += (size_t)M * N1 * 4;  // 537 MB

    hipMemsetAsync(d_ws, 0, 256, stream);  // zero amax slots (ws is poisoned 0xAA)

    amax_kernel<<<1024, 256, 0, stream>>>(x,  (long)M * K1,  amax_x);
    amax_kernel<<<1024, 256, 0, stream>>>(w1, (long)K1 * N1, amax_w1);
    amax_kernel<<<1024, 256, 0, stream>>>(w2, (long)N1 * N2, amax_w2);

    quant_kernel<<<2048, 256, 0, stream>>>(x, xq, amax_x, (long)M * K1);
    quant_transpose_kernel<<<dim3(N1 / 32, K1 / 32), 256, 0, stream>>>(w1, w1qT, amax_w1, K1, N1);
    quant_transpose_kernel<<<dim3(N2 / 32, N1 / 32), 256, 0, stream>>>(w2, w2qT, amax_w2, N1, N2);

    gemm_mxfp8_kernel<true, true><<<dim3(M / 128, N1 / 128), 256, 0, stream>>>(
        xq, w1qT, h, b1, amax_x, amax_w1, amax_h, M, N1, K1);

    quant_kernel<<<4096, 256, 0, stream>>>(h, hq, amax_h, (long)M * N1);

    gemm_mxfp8_kernel<false, false><<<dim3(M / 128, N2 / 128), 256, 0, stream>>>(
        hq, w2qT, out, b2, amax_h, amax_w2, nullptr, M, N2, N1);
}